// Round 2
// 1117.132 us; speedup vs baseline: 1.0127x; 1.0127x over previous
//
#include <hip/hip_runtime.h>
#include <hip/hip_bf16.h>
#include <stdint.h>

// Problem constants
#define B_  32
#define S_  2048
#define H_  1024
#define K_  2048   // 2H, GEMM reduction dim
#define M_  65536  // B*S

// Fallback GEMM tile config (fp32-A path)
#define BM  128
#define BN  128
#define BK  32
#define LDK 40     // padded LDS row stride for A in fallback path (bf16 elems)

typedef __bf16 bf16x8 __attribute__((ext_vector_type(8)));
typedef float  f32x4  __attribute__((ext_vector_type(4)));

__device__ __forceinline__ unsigned short f2bf(float x) {
    unsigned u = __builtin_bit_cast(unsigned, x);
    u += 0x7fffu + ((u >> 16) & 1u);
    return (unsigned short)(u >> 16);
}

__device__ __forceinline__ unsigned pk_bf16(float x, float y) {
#if __has_builtin(__builtin_amdgcn_cvt_pk_bf16_f32)
    auto r = __builtin_amdgcn_cvt_pk_bf16_f32(x, y);
    static_assert(sizeof(r) == 4, "cvt_pk_bf16 size");
    return __builtin_bit_cast(unsigned, r);
#else
    return ((unsigned)f2bf(x)) | ((unsigned)f2bf(y) << 16);
#endif
}

__device__ __forceinline__ float bf2f(unsigned u16) {
    return __builtin_bit_cast(float, u16 << 16);
}

__device__ __forceinline__ float tanh_fast(float x) {
    float e = __expf(2.0f * x);
    return 1.0f - 2.0f / (e + 1.0f);
}

// ---------------------------------------------------------------- fp32 -> bf16, 8 elems/thread, grid-stride
__global__ __launch_bounds__(256) void cast8_k(const float* __restrict__ in,
                                               unsigned short* __restrict__ o, long n8) {
    const long stride = (long)gridDim.x * 256;
    for (long i = (long)blockIdx.x * 256 + threadIdx.x; i < n8; i += stride) {
        const float4* p = (const float4*)(in + i * 8);
        float4 a = p[0], b = p[1];
        uint4 pk;
        pk.x = pk_bf16(a.x, a.y);
        pk.y = pk_bf16(a.z, a.w);
        pk.z = pk_bf16(b.x, b.y);
        pk.w = pk_bf16(b.z, b.w);
        *(uint4*)(o + i * 8) = pk;
    }
}

// ---------------------------------------------------------------- dec = dec_state @ W_dec^T
__global__ __launch_bounds__(256) void dec_k(const float* __restrict__ ds,
                                             const float* __restrict__ Wd,
                                             float* __restrict__ decv) {
    const int b = blockIdx.y;
    const int w = threadIdx.x >> 6, lane = threadIdx.x & 63;
    const int h = blockIdx.x * 4 + w;
    const float* wr = Wd + (long)h * H_;
    const float* dr = ds + (long)b * H_;
    float acc = 0.f;
#pragma unroll
    for (int i = 0; i < 4; i++) {
        int idx = lane * 4 + i * 256;
        float4 a = *(const float4*)(wr + idx);
        float4 d = *(const float4*)(dr + idx);
        acc += a.x * d.x + a.y * d.y + a.z * d.z + a.w * d.w;
    }
    for (int m2 = 1; m2 < 64; m2 <<= 1) acc += __shfl_xor(acc, m2, 64);
    if (lane == 0) decv[(long)b * H_ + h] = acc;
}

// ---------------------------------------------------------------- shared epilogue (fallback 128x128 path)
__device__ __forceinline__ void energy_epilogue(f32x4 acc[4][4], int mb, int nb,
                                                const float* decv, const float* Weng,
                                                float* pe, float esum[2][BM],
                                                int t, int wm, int wn, int r, int g) {
    const int b = mb >> 4;  // S/BM = 16 m-blocks per batch; tiles never straddle b
    float wv[4], dv[4];
#pragma unroll
    for (int ni = 0; ni < 4; ni++) {
        int h = nb * BN + wn * 64 + ni * 16 + r;  // C/D col = lane&15
        wv[ni] = Weng[h];
        dv[ni] = decv[b * H_ + h];
    }
    float rs[4][4];
#pragma unroll
    for (int mi = 0; mi < 4; mi++)
#pragma unroll
        for (int rr = 0; rr < 4; rr++) rs[mi][rr] = 0.f;
#pragma unroll
    for (int mi = 0; mi < 4; mi++)
#pragma unroll
        for (int ni = 0; ni < 4; ni++)
#pragma unroll
            for (int rr = 0; rr < 4; rr++)
                rs[mi][rr] += wv[ni] * tanh_fast(dv[ni] + acc[mi][ni][rr]);
#pragma unroll
    for (int m2 = 1; m2 < 16; m2 <<= 1)
#pragma unroll
        for (int mi = 0; mi < 4; mi++)
#pragma unroll
            for (int rr = 0; rr < 4; rr++)
                rs[mi][rr] += __shfl_xor(rs[mi][rr], m2, 64);
    if (r == 0) {
#pragma unroll
        for (int mi = 0; mi < 4; mi++)
#pragma unroll
            for (int rr = 0; rr < 4; rr++)
                esum[wn][wm * 64 + mi * 16 + g * 4 + rr] = rs[mi][rr];  // row=(lane>>4)*4+reg
    }
    __syncthreads();
    if (t < BM) pe[(long)nb * M_ + (long)mb * BM + t] = esum[0][t] + esum[1][t];
}

// ================================================================ FAST gemm:
// 256x256 tile, 8-phase pipeline (T3+T4), counted vmcnt, setprio (T5),
// fragment-ordered LDS (conflict-free ds_read_b128), XCD swizzle (T1).
//
// LDS layout: per matrix a ring of 4 k-half slots (k-half = 32 cols = one MFMA K).
//   Slot = 16 KB = 1024 granules of 16 B. Granule u = rowblk*64 + g*16 + r holds
//   elems [rowblk*16+r][khalf*32 + g*8 .. +7] — exactly the MFMA fragment layout,
//   so every ds_read_b128 is base + lane*16 (lane-linear, zero bank conflicts).
//   global_load_lds writes linearly (u = t, t+512); the per-lane GLOBAL source
//   address realizes the permutation (guide §5: pre-swizzled source, linear LDS).
//
// Robust wait discipline (r1 fix): WAIT4 at EVERY odd phase. Each inter-clobber
// window then contains exactly one kh's 4 loads, so vmcnt(4) at the window end
// completes the whole previous window regardless of any compiler reordering of
// the DMA calls within a window (and regardless of hoisted scalar loads).
// Publish margin: each slot's data is waited + barrier-published >=2 barriers
// before its first ds_read; ds_read hoisting is bounded by the previous asm
// memory clobber, which always lies after the publish barrier. offset arg of
// global_load_lds is always 0 (kh offsets folded into the pointers).
//
//   p0: rd s0 miL | stage A(kh+3)->s3      p1: rd s0 miH | stage B(kh+3)->s3 +W4
//   p2: rd s1 miL | stage A(kh+4)->s0      p3: rd s1 miH | stage B(kh+4)->s0 +W4
//   p4: rd s2 miL | stage A(kh+5)->s1      p5: rd s2 miH | stage B(kh+5)->s1 +W4
//   p6: rd s3 miL | stage A(kh+6)->s2      p7: rd s3 miH | stage B(kh+6)->s2 +W4
#define GBM 256
#define GBN 256

#define LDA_(SLOT, RB) (*(const bf16x8*)&LDS[(SLOT) * 8192 + ((RB) * 64 + lane) * 8])
#define LDB_(SLOT, RB) (*(const bf16x8*)&LDS[32768 + (SLOT) * 8192 + ((RB) * 64 + lane) * 8])

#define STAGE_A(KOFF, SLOT) do { \
    __builtin_amdgcn_global_load_lds((const __attribute__((address_space(1))) unsigned*)(aQ + (KOFF)), \
        (__attribute__((address_space(3))) unsigned*)&LDS[(SLOT) * 8192 + t * 8], 16, 0, 0); \
    __builtin_amdgcn_global_load_lds((const __attribute__((address_space(1))) unsigned*)(aQ2 + (KOFF)), \
        (__attribute__((address_space(3))) unsigned*)&LDS[(SLOT) * 8192 + 4096 + t * 8], 16, 0, 0); \
} while (0)

#define STAGE_B(KOFF, SLOT) do { \
    __builtin_amdgcn_global_load_lds((const __attribute__((address_space(1))) unsigned*)(bQ + (KOFF)), \
        (__attribute__((address_space(3))) unsigned*)&LDS[32768 + (SLOT) * 8192 + t * 8], 16, 0, 0); \
    __builtin_amdgcn_global_load_lds((const __attribute__((address_space(1))) unsigned*)(bQ2 + (KOFF)), \
        (__attribute__((address_space(3))) unsigned*)&LDS[32768 + (SLOT) * 8192 + 4096 + t * 8], 16, 0, 0); \
} while (0)

#define NOSTAGE do {} while (0)
#define WAIT4 asm volatile("s_waitcnt vmcnt(4)" ::: "memory")
#define WAIT0 asm volatile("s_waitcnt vmcnt(0)" ::: "memory")
#define NOWAIT do {} while (0)

#define PHASE(SLOT, MH, LOADB, STG, WSTMT) do { \
    bf16x8 a0 = LDA_(SLOT, WR8 + (MH) * 4 + 0); \
    bf16x8 a1 = LDA_(SLOT, WR8 + (MH) * 4 + 1); \
    bf16x8 a2 = LDA_(SLOT, WR8 + (MH) * 4 + 2); \
    bf16x8 a3 = LDA_(SLOT, WR8 + (MH) * 4 + 3); \
    if (LOADB) { \
        bq0 = LDB_(SLOT, WC4 + 0); \
        bq1 = LDB_(SLOT, WC4 + 1); \
        bq2 = LDB_(SLOT, WC4 + 2); \
        bq3 = LDB_(SLOT, WC4 + 3); \
    } \
    STG; \
    __builtin_amdgcn_s_barrier(); \
    __builtin_amdgcn_s_setprio(1); \
    acc[(MH)*4+0][0] = __builtin_amdgcn_mfma_f32_16x16x32_bf16(a0, bq0, acc[(MH)*4+0][0], 0, 0, 0); \
    acc[(MH)*4+0][1] = __builtin_amdgcn_mfma_f32_16x16x32_bf16(a0, bq1, acc[(MH)*4+0][1], 0, 0, 0); \
    acc[(MH)*4+0][2] = __builtin_amdgcn_mfma_f32_16x16x32_bf16(a0, bq2, acc[(MH)*4+0][2], 0, 0, 0); \
    acc[(MH)*4+0][3] = __builtin_amdgcn_mfma_f32_16x16x32_bf16(a0, bq3, acc[(MH)*4+0][3], 0, 0, 0); \
    acc[(MH)*4+1][0] = __builtin_amdgcn_mfma_f32_16x16x32_bf16(a1, bq0, acc[(MH)*4+1][0], 0, 0, 0); \
    acc[(MH)*4+1][1] = __builtin_amdgcn_mfma_f32_16x16x32_bf16(a1, bq1, acc[(MH)*4+1][1], 0, 0, 0); \
    acc[(MH)*4+1][2] = __builtin_amdgcn_mfma_f32_16x16x32_bf16(a1, bq2, acc[(MH)*4+1][2], 0, 0, 0); \
    acc[(MH)*4+1][3] = __builtin_amdgcn_mfma_f32_16x16x32_bf16(a1, bq3, acc[(MH)*4+1][3], 0, 0, 0); \
    acc[(MH)*4+2][0] = __builtin_amdgcn_mfma_f32_16x16x32_bf16(a2, bq0, acc[(MH)*4+2][0], 0, 0, 0); \
    acc[(MH)*4+2][1] = __builtin_amdgcn_mfma_f32_16x16x32_bf16(a2, bq1, acc[(MH)*4+2][1], 0, 0, 0); \
    acc[(MH)*4+2][2] = __builtin_amdgcn_mfma_f32_16x16x32_bf16(a2, bq2, acc[(MH)*4+2][2], 0, 0, 0); \
    acc[(MH)*4+2][3] = __builtin_amdgcn_mfma_f32_16x16x32_bf16(a2, bq3, acc[(MH)*4+2][3], 0, 0, 0); \
    acc[(MH)*4+3][0] = __builtin_amdgcn_mfma_f32_16x16x32_bf16(a3, bq0, acc[(MH)*4+3][0], 0, 0, 0); \
    acc[(MH)*4+3][1] = __builtin_amdgcn_mfma_f32_16x16x32_bf16(a3, bq1, acc[(MH)*4+3][1], 0, 0, 0); \
    acc[(MH)*4+3][2] = __builtin_amdgcn_mfma_f32_16x16x32_bf16(a3, bq2, acc[(MH)*4+3][2], 0, 0, 0); \
    acc[(MH)*4+3][3] = __builtin_amdgcn_mfma_f32_16x16x32_bf16(a3, bq3, acc[(MH)*4+3][3], 0, 0, 0); \
    __builtin_amdgcn_s_setprio(0); \
    WSTMT; \
    __builtin_amdgcn_s_barrier(); \
} while (0)

__global__ __launch_bounds__(512, 2) void gemm_fast(const unsigned short* __restrict__ Abf,
                                                    const unsigned short* __restrict__ Bw,
                                                    const float* __restrict__ decv,
                                                    const float* __restrict__ Weng,
                                                    float* __restrict__ pe) {
    __shared__ __align__(1024) unsigned short LDS[65536];  // 128 KiB: A ring 64K | B ring 64K

    // Bijective XCD swizzle: 4 nb-blocks of an mb land on one XCD (A L2 reuse).
    const int L = blockIdx.x;
    const int xcd = L & 7;
    const int sl = L >> 3;          // 0..127
    const int nb = sl & 3;          // 4 n-blocks (N=1024)
    const int mb = (sl >> 2) * 8 + xcd;  // 0..255

    const int t = threadIdx.x;
    const int lane = t & 63;
    const int w = t >> 6;           // 8 waves: 2M x 4N
    const int WR = w >> 2, WC = w & 3;
    const int WR8 = WR * 8, WC4 = WC * 4;
    const int r = lane & 15, g = (lane >> 4) & 3;

    f32x4 acc[8][4];
#pragma unroll
    for (int mi = 0; mi < 8; mi++)
#pragma unroll
        for (int ni = 0; ni < 4; ni++)
#pragma unroll
            for (int k = 0; k < 4; k++) acc[mi][ni][k] = 0.f;
    bf16x8 bq0, bq1, bq2, bq3;

    // Per-thread staging source (fragment-order permutation): thread t stages
    // granules u=t (rowblk t>>6) and u=t+512 (rowblk +8).
    const int srow = ((t >> 6) << 4) + (t & 15);
    const int scol = ((t >> 4) & 3) << 3;
    const unsigned short* aQ  = Abf + (long)(mb * GBM + srow) * K_ + scol;
    const unsigned short* aQ2 = aQ + 128L * K_;
    const unsigned short* bQ  = Bw + (long)(nb * GBN + srow) * K_ + scol;
    const unsigned short* bQ2 = bQ + 128L * K_;

    // Prologue: stage kh 0,1,2 (A+B each); WAIT4 completes kh0,kh1; kh2 in flight.
    STAGE_A(0, 0);   STAGE_B(0, 0);
    STAGE_A(32, 1);  STAGE_B(32, 1);
    STAGE_A(64, 2);  STAGE_B(64, 2);
    WAIT4;
    __builtin_amdgcn_s_barrier();

#pragma unroll 1
    for (int i = 0; i < 15; ++i) {
        PHASE(0, 0, 1, STAGE_A(96, 3), NOWAIT);
        PHASE(0, 1, 0, STAGE_B(96, 3), WAIT4);   // completes kh+2 (slot2)
        PHASE(1, 0, 1, STAGE_A(128, 0), NOWAIT);
        PHASE(1, 1, 0, STAGE_B(128, 0), WAIT4);  // completes kh+3 (slot3)
        PHASE(2, 0, 1, STAGE_A(160, 1), NOWAIT);
        PHASE(2, 1, 0, STAGE_B(160, 1), WAIT4);  // completes kh+4 (slot0)
        PHASE(3, 0, 1, STAGE_A(192, 2), NOWAIT);
        PHASE(3, 1, 0, STAGE_B(192, 2), WAIT4);  // completes kh+5 (slot1)
        aQ += 128; aQ2 += 128; bQ += 128; bQ2 += 128;  // advance 4 k-halves
    }
    // Final iteration: only kh63 left to stage (base kh60 after 15 iters).
    PHASE(0, 0, 1, STAGE_A(96, 3), NOWAIT);
    PHASE(0, 1, 0, STAGE_B(96, 3), WAIT4);       // completes kh62 (slot2)
    PHASE(1, 0, 1, NOSTAGE, NOWAIT);
    PHASE(1, 1, 0, NOSTAGE, WAIT0);              // completes kh63 (slot3)
    PHASE(2, 0, 1, NOSTAGE, NOWAIT);
    PHASE(2, 1, 0, NOSTAGE, NOWAIT);
    PHASE(3, 0, 1, NOSTAGE, NOWAIT);
    PHASE(3, 1, 0, NOSTAGE, NOWAIT);

    // ---------------- energy epilogue: rs[m] = sum_h Weng[h]*tanh(dec[b,h]+C[m,h])
    const int b = mb >> 3;  // 8 m-blocks per batch; tiles never straddle b
    float wv[4], dv[4];
#pragma unroll
    for (int ni = 0; ni < 4; ni++) {
        int h = nb * GBN + WC4 * 16 + ni * 16 + r;  // C/D col = lane&15
        wv[ni] = Weng[h];
        dv[ni] = decv[b * H_ + h];
    }
    float rs[8][4];
#pragma unroll
    for (int mi = 0; mi < 8; mi++)
#pragma unroll
        for (int rr = 0; rr < 4; rr++) rs[mi][rr] = 0.f;
#pragma unroll
    for (int mi = 0; mi < 8; mi++)
#pragma unroll
        for (int ni = 0; ni < 4; ni++)
#pragma unroll
            for (int rr = 0; rr < 4; rr++)
                rs[mi][rr] += wv[ni] * tanh_fast(dv[ni] + acc[mi][ni][rr]);
#pragma unroll
    for (int m2 = 1; m2 < 16; m2 <<= 1)
#pragma unroll
        for (int mi = 0; mi < 8; mi++)
#pragma unroll
            for (int rr = 0; rr < 4; rr++)
                rs[mi][rr] += __shfl_xor(rs[mi][rr], m2, 64);
    float* esumF = (float*)&LDS[0];  // reuse LDS: 4 WC-planes x 256 rows
    if (r == 0) {
#pragma unroll
        for (int mi = 0; mi < 8; mi++)
#pragma unroll
            for (int rr = 0; rr < 4; rr++)
                esumF[WC * 256 + WR * 128 + mi * 16 + g * 4 + rr] = rs[mi][rr];
    }
    __syncthreads();
    if (t < 256) {
        float s = esumF[t] + esumF[256 + t] + esumF[512 + t] + esumF[768 + t];
        pe[(long)nb * M_ + (long)mb * 256 + t] = s;
    }
}

// ---------------------------------------------------------------- FALLBACK gemm (fp32 A, in-kernel cvt)
__global__ __launch_bounds__(256) void gemm_energy(const float* __restrict__ A,
                                                   const unsigned short* __restrict__ Bw,
                                                   const float* __restrict__ decv,
                                                   const float* __restrict__ Weng,
                                                   float* __restrict__ pe) {
    __shared__ __align__(16) unsigned short Asm[BM * LDK];
    __shared__ __align__(1024) unsigned short Bsm[BN * BK];
    __shared__ float esum[2][BM];

    const int L = blockIdx.x;
    const int xcd = L & 7;
    const int slot = L >> 3;
    const int nb = slot & 7;
    const int mb = (slot >> 3) * 8 + xcd;

    const int t = threadIdx.x;
    const int lane = t & 63, w = t >> 6;
    const int wm = w >> 1, wn = w & 1;
    const int r = lane & 15, g = lane >> 4;

    f32x4 acc[4][4];
#pragma unroll
    for (int mi = 0; mi < 4; mi++)
#pragma unroll
        for (int ni = 0; ni < 4; ni++)
#pragma unroll
            for (int k = 0; k < 4; k++) acc[mi][ni][k] = 0.f;

    const float* Abase = A + (long)mb * BM * K_;
    const unsigned short* Bbase = Bw + (long)nb * BN * K_;

    for (int kt = 0; kt < K_; kt += BK) {
        __syncthreads();
#pragma unroll
        for (int j = 0; j < 2; j++) {
            int u = t + 256 * j;
            int row = u >> 2, c8 = (u & 3) << 3;
            __builtin_amdgcn_global_load_lds(
                (const __attribute__((address_space(1))) unsigned*)(Bbase + (long)row * K_ + kt + c8),
                (__attribute__((address_space(3))) unsigned*)&Bsm[u * 8], 16, 0, 0);
        }
#pragma unroll
        for (int i = 0; i < 4; i++) {
            int f = t + 256 * i;
            int row = f >> 3, c4 = (f & 7) << 2;
            float4 v = *(const float4*)(Abase + (long)row * K_ + kt + c4);
            uint2 pk;
            pk.x = pk_bf16(v.x, v.y);
            pk.y = pk_bf16(v.z, v.w);
            *(uint2*)&Asm[row * LDK + c4] = pk;
        }
        __syncthreads();
        bf16x8 af[4], bfr[4];
#pragma unroll
        for (int mi = 0; mi < 4; mi++)
            af[mi] = *(const bf16x8*)&Asm[(wm * 64 + mi * 16 + r) * LDK + g * 8];
#pragma unroll
        for (int ni = 0; ni < 4; ni++)
            bfr[ni] = *(const bf16x8*)&Bsm[(wn * 64 + ni * 16 + r) * BK + g * 8];
#pragma unroll
        for (int mi = 0; mi < 4; mi++)
#pragma unroll
            for (int ni = 0; ni < 4; ni++)
                acc[mi][ni] = __builtin_amdgcn_mfma_f32_16x16x32_bf16(af[mi], bfr[ni],
                                                                     acc[mi][ni], 0, 0, 0);
    }
    energy_epilogue(acc, mb, nb, decv, Weng, pe, esum, t, wm, wn, r, g);
}

// ---------------------------------------------------------------- masked softmax over s (np partial planes)
__global__ __launch_bounds__(256) void softmax_k(const float* __restrict__ pe,
                                                 const int* __restrict__ slen,
                                                 float* __restrict__ alph, int np) {
    const int b = blockIdx.x, t = threadIdx.x;
    const int len = slen[b];
    __shared__ float sh[4];
    const float NEG = -__builtin_inff();
    float e[8];
    float mx = NEG;
#pragma unroll
    for (int i = 0; i < 8; i++) {
        int s = t + i * 256;
        float v = 0.f;
        for (int p = 0; p < np; p++) v += pe[(long)p * M_ + b * S_ + s];
        v = (s < len) ? v : NEG;
        e[i] = v;
        mx = fmaxf(mx, v);
    }
    for (int m2 = 1; m2 < 64; m2 <<= 1) mx = fmaxf(mx, __shfl_xor(mx, m2, 64));
    if ((t & 63) == 0) sh[t >> 6] = mx;
    __syncthreads();
    mx = fmaxf(fmaxf(sh[0], sh[1]), fmaxf(sh[2], sh[3]));
    float sum = 0.f;
#pragma unroll
    for (int i = 0; i < 8; i++) {
        float x = (e[i] == NEG) ? 0.f : __expf(e[i] - mx);
        e[i] = x;
        sum += x;
    }
    for (int m2 = 1; m2 < 64; m2 <<= 1) sum += __shfl_xor(sum, m2, 64);
    __syncthreads();
    if ((t & 63) == 0) sh[t >> 6] = sum;
    __syncthreads();
    sum = sh[0] + sh[1] + sh[2] + sh[3];
    float inv = 1.0f / sum;
#pragma unroll
    for (int i = 0; i < 8; i++) alph[b * S_ + t + i * 256] = e[i] * inv;
}

// ---------------------------------------------------------------- context (bf16 enc copy), fine-grained
__global__ __launch_bounds__(256) void context_bf(const unsigned short* __restrict__ encbf,
                                                  const float* __restrict__ alph,
                                                  const int* __restrict__ slen,
                                                  float* __restrict__ out) {
    const int slot = blockIdx.x;
    const int b = slot & 31, sc = slot >> 5;
    const int len = slen[b];
    const int s0 = sc * 64;
    if (s0 >= len) return;
    const int send = min(s0 + 64, len);
    __shared__ float al[64];
    const int t = threadIdx.x;
    if (t < 64) al[t] = alph[b * S_ + s0 + t];
    __syncthreads();
    const unsigned short* base = encbf + ((long)b * S_ + s0) * K_ + t * 8;
    float ac[8];
#pragma unroll
    for (int j = 0; j < 8; j++) ac[j] = 0.f;
#pragma unroll 4
    for (int s = s0; s < send; ++s) {
        float a = al[s - s0];
        uint4 v = *(const uint4*)base;
        ac[0] += a * bf2f(v.x & 0xffffu);
        ac[1] += a * bf2f(v.x >> 16);
        ac[2] += a * bf2f(v.y & 0xffffu);
        ac[3] += a * bf2f(v.y >> 16);
        ac[4] += a * bf2f(v.z & 0xffffu);
        ac[5] += a * bf2f(v.z >> 16);
        ac[6] += a * bf2f(v.w & 0xffffu);
        ac[7] += a * bf2f(v.w >> 16);
        base += K_;
    }
    float* o = out + (long)b * K_ + t * 8;
#pragma unroll
    for (int j = 0; j < 8; j++) atomicAdd(o + j, ac[j]);
}

// ---------------------------------------------------------------- context (fp32), fine-grained fallback
__global__ __launch_bounds__(256) void context_f32(const float* __restrict__ enc,
                                                   const float* __restrict__ alph,
                                                   const int* __restrict__ slen,
                                                   float* __restrict__ out) {
    const int slot = blockIdx.x;
    const int b = slot & 31, ec = (slot >> 5) & 1, sc = slot >> 6;
    const int len = slen[b];
    const int s0 = sc * 64;
    if (s0 >= len) return;
    const int send = min(s0 + 64, len);
    __shared__ float al[64];
    const int t = threadIdx.x;
    if (t < 64) al[t] = alph[b * S_ + s0 + t];
    __syncthreads();
    const int e0 = ec * 1024 + t * 4;
    const float* base = enc + ((long)b * S_ + s0) * K_ + e0;
    float ax = 0.f, ay = 0.f, az = 0.f, aw = 0.f;
#pragma unroll 4
    for (int s = s0; s < send; ++s) {
        float a = al[s - s0];
        float4 v = *(const float4*)base;
        ax += a * v.x; ay += a * v.y; az += a * v.z; aw += a * v.w;
        base += K_;
    }
    float* o = out + (long)b * K_ + e0;
    atomicAdd(o + 0, ax);
    atomicAdd(o + 1, ay);
    atomicAdd(o + 2, az);
    atomicAdd(o + 3, aw);
}

extern "C" void kernel_launch(void* const* d_in, const int* in_sizes, int n_in,
                              void* d_out, int out_size, void* d_ws, size_t ws_size,
                              hipStream_t stream) {
    const float* dec_state = (const float*)d_in[0];  // [32,1,1024]
    const float* enc_state = (const float*)d_in[1];  // [32,2048,2048]
    const int*   src_len   = (const int*)d_in[2];    // [32]
    const float* W_enc     = (const float*)d_in[3];  // [1024,2048]
    const float* W_dec     = (const float*)d_in[4];  // [1024,1024]
    const float* W_energy  = (const float*)d_in[5];  // [1,1024]
    float* out = (float*)d_out;  // [0,65536): context [32,2048]; [65536,131072): alphas [32,2048]

    char* ws = (char*)d_ws;
    float* decv = (float*)ws;                                           // 128 KB @ 0
    float* pe   = (float*)(ws + (1 << 17));                             // 2 MB @ 128K
    unsigned short* Wenc_bf = (unsigned short*)(ws + 3 * (1 << 20));    // 4 MB @ 3M
    unsigned short* Abf = (unsigned short*)(ws + 8 * (1 << 20));        // 256 MB @ 8M
    float* alph = out + 65536;

    const size_t need_fast = 8ull * (1 << 20) + (size_t)M_ * K_ * 2;  // 8M + 256M

    hipMemsetAsync(out, 0, 65536 * sizeof(float), stream);

    cast8_k<<<1024, 256, 0, stream>>>(W_enc, Wenc_bf, (long)H_ * K_ / 8);
    dec_k<<<dim3(H_ / 4, B_), 256, 0, stream>>>(dec_state, W_dec, decv);

    if (ws_size >= need_fast) {
        cast8_k<<<2048, 256, 0, stream>>>(enc_state, Abf, (long)M_ * K_ / 8);
        gemm_fast<<<1024, 512, 0, stream>>>(Abf, Wenc_bf, decv, W_energy, pe);
        softmax_k<<<B_, 256, 0, stream>>>(pe, src_len, alph, 4);
        context_bf<<<1024, 256, 0, stream>>>(Abf, alph, src_len, out);
    } else {
        gemm_energy<<<4096, 256, 0, stream>>>(enc_state, Wenc_bf, decv, W_energy, pe);
        softmax_k<<<B_, 256, 0, stream>>>(pe, src_len, alph, 8);
        context_f32<<<2048, 256, 0, stream>>>(enc_state, alph, src_len, out);
    }
}